// Round 1
// baseline (174.865 us; speedup 1.0000x reference)
//
#include <hip/hip_runtime.h>

#define AFROMZERO 0.02f
#define AFROMC    0.01f
#define OSF       15.0f
#define EXPMAX    50.0f

// zmax_calc with c = 1.0 (as used by likelihood()).
__device__ __forceinline__ float zmax_calc(float a, float b) {
    if (a < AFROMZERO) {
        // z_zero = (c > b) ? b/c : 1.0  with c=1  -> min(b, 1)
        return fminf(b, 1.0f);
    }
    if (fabsf(a - 1.0f) < AFROMC) {
        return b / (b + 1.0f);
    }
    float denom = 1.0f - a;
    float d = (b - 1.0f) * (b - 1.0f) + 4.0f * a * b;
    float zg = 0.5f * (b + 1.0f - sqrtf(d)) / denom;
    if (zg > 0.9999f && b > 100.0f) zg = fminf(zg, 1.0f - a / b);
    return zg;
}

// Per-(param set, m) constants:
//   f_exp(z) = C - be/z - log(z) + aeff*log(1-z)
// where C = be/zmax + log(zmax) - aeff*log(1-zmax), be = b*mT^2,
// and aeff = 0 when a < AFROMZERO (a_coef dropped in reference).
__device__ __forceinline__ void set_consts(float a, float b, float mTv,
                                           float& C, float& be) {
    be = b * mTv * mTv;
    float zm  = zmax_calc(a, be);
    float inv = 1.0f / zm;
    float c   = be * inv + logf(zm);
    if (a >= AFROMZERO) c -= a * logf(1.0f - zm);   // guard: zm may be 1 when a<AFROMZERO
    C = c;
}

__global__ __launch_bounds__(256) void lund_weight_kernel(
    const float* __restrict__ z,      // (B, 128, 25)
    const float* __restrict__ mT,     // (B, 128)
    const int*   __restrict__ obs,    // (B, 2) -> mult = obs[2b]
    const float* __restrict__ pa_p,   // scalar
    const float* __restrict__ pb_p,   // scalar
    const float* __restrict__ base_p, // (2,)
    float* __restrict__ out)          // (B,)
{
    const int b   = blockIdx.x;
    const int tid = threadIdx.x;

    const float pa = pa_p[0];
    const float pb = pb_p[0];
    const float a0 = base_p[0];
    const float b0 = base_p[1];
    const float aeff_n = (pa < AFROMZERO) ? 0.0f : pa;
    const float aeff_o = (a0 < AFROMZERO) ? 0.0f : a0;
    const int   mult   = obs[2 * b];

    __shared__ float4 s_p[128];     // {C_new, be_new, C_old, be_old} per m
    __shared__ double s_part[4];

    if (tid < 128) {
        float mTv = mT[(size_t)b * 128 + tid];
        float Cn, ben, Co, beo;
        set_consts(pa, pb, mTv, Cn, ben);
        set_consts(a0, b0, mTv, Co, beo);
        s_p[tid] = make_float4(Cn, ben, Co, beo);
    }
    __syncthreads();

    const float4* zrow = (const float4*)(z + (size_t)b * 3200);
    double prod = 1.0;

    for (int i = tid; i < 800; i += 256) {
        float4 zv = zrow[i];
        int e = 4 * i;
        int m = e / 25;
        int r = e - 25 * m;
        float zza[4] = {zv.x, zv.y, zv.z, zv.w};
        #pragma unroll
        for (int j = 0; j < 4; ++j) {
            float zz = zza[j];
            bool active = (zz != 0.0f) && (m < mult);
            float zs = active ? zz : 0.5f;        // avoid NaN paths for masked lanes
            float4 p = s_p[m];

            float rz = __builtin_amdgcn_rcpf(zs);
            float lz = __logf(zs);
            float l1 = __logf(1.0f - zs);

            float fn = fmaf(-p.y, rz, p.x) - lz + aeff_n * l1;
            float fo = fmaf(-p.w, rz, p.z) - lz + aeff_o * l1;
            fn = fminf(fmaxf(fn, -EXPMAX), EXPMAX);
            fo = fminf(fmaxf(fo, -EXPMAX), EXPMAX);
            float Ln = __expf(fn);
            float Lo = __expf(fo);

            // r==0: accepted -> Ln/Lo ; r>0: rejected -> (OSF-Ln)/(OSF-Lo)
            float num = (r == 0) ? Ln : (OSF - Ln);
            float den = (r == 0) ? Lo : (OSF - Lo);
            float w = active ? (num * __builtin_amdgcn_rcpf(den)) : 1.0f;
            prod *= (double)w;

            if (++r == 25) { r = 0; ++m; }
        }
    }

    // wave (64-lane) product reduction
    for (int mask = 1; mask < 64; mask <<= 1)
        prod *= __shfl_xor(prod, mask, 64);
    if ((tid & 63) == 0) s_part[tid >> 6] = prod;
    __syncthreads();
    if (tid == 0)
        out[b] = (float)(s_part[0] * s_part[1] * s_part[2] * s_part[3]);
}

extern "C" void kernel_launch(void* const* d_in, const int* in_sizes, int n_in,
                              void* d_out, int out_size, void* d_ws, size_t ws_size,
                              hipStream_t stream) {
    const float* z    = (const float*)d_in[0];
    const float* mT   = (const float*)d_in[1];
    const int*   obs  = (const int*)d_in[2];
    const float* pa   = (const float*)d_in[3];
    const float* pb   = (const float*)d_in[4];
    const float* base = (const float*)d_in[5];
    float* out = (float*)d_out;

    int B = in_sizes[0] / (128 * 25);   // z is (B, 128, 25)
    lund_weight_kernel<<<B, 256, 0, stream>>>(z, mT, obs, pa, pb, base, out);
}

// Round 2
// 162.963 us; speedup vs baseline: 1.0730x; 1.0730x over previous
//
#include <hip/hip_runtime.h>

#define AFROMZERO 0.02f
#define AFROMC    0.01f
#define OSF       15.0f
#define LOG2E     1.4426950408889634f
#define EXPMAX2   (50.0f * LOG2E)   // reference clips f_exp to +/-50 (natural log units)

// zmax_calc with c = 1.0 (as used by likelihood()).
__device__ __forceinline__ float zmax_calc(float a, float b) {
    if (a < AFROMZERO) return fminf(b, 1.0f);          // c=1: (c>b)? b/c : 1
    if (fabsf(a - 1.0f) < AFROMC) return b / (b + 1.0f);
    float d  = (b - 1.0f) * (b - 1.0f) + 4.0f * a * b;
    float zg = 0.5f * (b + 1.0f - sqrtf(d)) / (1.0f - a);
    if (zg > 0.9999f && b > 100.0f) zg = fminf(zg, 1.0f - a / b);
    return zg;
}

// Base-2 per-(param,m) constants:
//   f2(z) = C2 - be2*(1/z) - log2(z) + a*log2(1-z)   ==  f_exp * log2(e)
//   L(z)  = exp2(clamp(f2, -EXPMAX2, EXPMAX2))
__device__ __forceinline__ void set_consts2(float a, float b, float mTv,
                                            float& C2, float& be2) {
    float be = b * mTv * mTv;
    float zm = zmax_calc(a, be);
    be2 = be * LOG2E;
    float c = be2 / zm + log2f(zm);
    if (a >= AFROMZERO) c -= a * log2f(1.0f - zm);   // a_coef dropped when a<AFROMZERO
    C2 = c;
}

__global__ __launch_bounds__(256) void lund_weight_kernel(
    const float* __restrict__ z,      // (B, 128, 25)
    const float* __restrict__ mT,     // (B, 128)
    const int*   __restrict__ obs,    // (B, 2) int32 -> mult = obs[2b]
    const float* __restrict__ pa_p,
    const float* __restrict__ pb_p,
    const float* __restrict__ base_p, // (2,)
    float* __restrict__ out)          // (B,)
{
    __shared__ float4 s_z4[1600];     // 2 rows x 3200 floats = 25.6 KB
    __shared__ float  s_part[4];
    float* s_z = (float*)s_z4;

    const int tid = threadIdx.x;
    const int r0  = blockIdx.x * 2;   // this block handles batch rows r0, r0+1

    const int mult0 = obs[2 * r0];
    const int mult1 = obs[2 * r0 + 2];
    // stage only the m < mult prefix of each row (rest of the row is never read)
    const int n4_0 = (mult0 * 25 + 3) >> 2;
    const int n4_1 = (mult1 * 25 + 3) >> 2;
    const float4* g = (const float4*)(z + (size_t)r0 * 3200);
    for (int i = tid; i < 800; i += 256) {
        if (i < n4_0) s_z4[i]       = g[i];
        if (i < n4_1) s_z4[800 + i] = g[800 + i];
    }

    // per-thread (param,m) constants — computed while staging loads are in flight
    const int  half = tid >> 7;       // 0 -> row r0, 1 -> row r0+1
    const int  m    = tid & 127;
    const int  row  = r0 + half;
    const int  mult = half ? mult1 : mult0;
    const bool live = m < mult;

    const float pa = pa_p[0], pb = pb_p[0];
    const float a0 = base_p[0], b0 = base_p[1];
    const float an = (pa < AFROMZERO) ? 0.0f : pa;
    const float ao = (a0 < AFROMZERO) ? 0.0f : a0;

    const float mTv = mT[(size_t)row * 128 + m];
    float Cn2, ben2, Co2, beo2;
    set_consts2(pa, pb, mTv, Cn2, ben2);
    set_consts2(a0, b0, mTv, Co2, beo2);

    __syncthreads();

    float w = 1.0f;
    if (live) {
        // lanes read stride-25 floats: gcd(25,32)=1 -> conflict-free (2 lanes/bank)
        const float* zp = s_z + half * 3200 + m * 25;
        float facN = 1.0f, facD = 1.0f;
        #pragma unroll
        for (int k = 0; k < 25; ++k) {
            float zz  = zp[k];
            bool  act = (zz != 0.0f);
            float zs  = act ? zz : 0.5f;
            float rz  = __builtin_amdgcn_rcpf(zs);
            float lz  = __builtin_amdgcn_logf(zs);          // log2
            float l1  = __builtin_amdgcn_logf(1.0f - zs);   // log2
            float fn  = fmaf(-ben2, rz, Cn2) + fmaf(an, l1, -lz);
            float fo  = fmaf(-beo2, rz, Co2) + fmaf(ao, l1, -lz);
            fn = fminf(fmaxf(fn, -EXPMAX2), EXPMAX2);
            fo = fminf(fmaxf(fo, -EXPMAX2), EXPMAX2);
            float Ln = __builtin_amdgcn_exp2f(fn);
            float Lo = __builtin_amdgcn_exp2f(fo);
            // k==0: accepted -> L/L0 ; k>0: rejected -> (OSF-L)/(OSF-L0)
            float fN = (k == 0) ? Ln : (OSF - Ln);
            float fD = (k == 0) ? Lo : (OSF - Lo);
            facN *= act ? fN : 1.0f;
            facD *= act ? fD : 1.0f;
        }
        w = facN / facD;   // one divide per 25 elements instead of per-element rcp
    }

    // 64-lane product reduction (wave0/1 -> row r0, wave2/3 -> row r0+1)
    for (int mask = 1; mask < 64; mask <<= 1)
        w *= __shfl_xor(w, mask, 64);
    if ((tid & 63) == 0) s_part[tid >> 6] = w;
    __syncthreads();
    if (tid == 0)   out[r0]     = s_part[0] * s_part[1];
    if (tid == 128) out[r0 + 1] = s_part[2] * s_part[3];
}

extern "C" void kernel_launch(void* const* d_in, const int* in_sizes, int n_in,
                              void* d_out, int out_size, void* d_ws, size_t ws_size,
                              hipStream_t stream) {
    const float* z    = (const float*)d_in[0];
    const float* mT   = (const float*)d_in[1];
    const int*   obs  = (const int*)d_in[2];
    const float* pa   = (const float*)d_in[3];
    const float* pb   = (const float*)d_in[4];
    const float* base = (const float*)d_in[5];
    float* out = (float*)d_out;

    int B = in_sizes[0] / (128 * 25);   // z is (B, 128, 25)
    lund_weight_kernel<<<B / 2, 256, 0, stream>>>(z, mT, obs, pa, pb, base, out);
}

// Round 3
// 158.436 us; speedup vs baseline: 1.1037x; 1.0286x over previous
//
#include <hip/hip_runtime.h>

#define AFROMZERO 0.02f
#define AFROMC    0.01f
#define OSF       15.0f
#define LOG2E     1.4426950408889634f
#define EXPMAX2   (50.0f * LOG2E)   // reference clips f_exp at +/-50 in natural-log units

// zmax_calc with c = 1.0 (as used by likelihood()).
__device__ __forceinline__ float zmax_calc(float a, float b) {
    if (a < AFROMZERO) return fminf(b, 1.0f);          // c=1: (c>b)? b/c : 1
    if (fabsf(a - 1.0f) < AFROMC) return b / (b + 1.0f);
    float d  = (b - 1.0f) * (b - 1.0f) + 4.0f * a * b;
    float zg = 0.5f * (b + 1.0f - sqrtf(d)) / (1.0f - a);
    if (zg > 0.9999f && b > 100.0f) zg = fminf(zg, 1.0f - a / b);
    return zg;
}

// Base-2 per-(param,m) constants:
//   f2(z) = C2 - be2*(1/z) - log2(z) + a*log2(1-z)  ==  f_exp * log2(e)
__device__ __forceinline__ void set_consts2(float a, float b, float mTv,
                                            float& C2, float& be2) {
    float be = b * mTv * mTv;
    float zm = zmax_calc(a, be);
    be2 = be * LOG2E;
    float c = be2 / zm + log2f(zm);
    if (a >= AFROMZERO) c -= a * log2f(1.0f - zm);
    C2 = c;
}

typedef const __attribute__((address_space(1))) void* as1_cvp;
typedef __attribute__((address_space(3))) void* as3_vp;

__global__ __launch_bounds__(256) void lund_weight_kernel(
    const float* __restrict__ z,      // (B, 128, 25)
    const float* __restrict__ mT,     // (B, 128)
    const int*   __restrict__ obs,    // (B, 2) -> mult = obs[2b]
    const float* __restrict__ pa_p,
    const float* __restrict__ pb_p,
    const float* __restrict__ base_p, // (2,)
    float* __restrict__ out)          // (B,)
{
    // row0 at s_z[0..3328), row1 at s_z[3328..6656) (1KB-chunk-aligned bases,
    // +128-float slack per row so tail chunks never overflow)
    __shared__ float s_z[6656];
    __shared__ float s_part[4];

    const int tid  = threadIdx.x;
    const int lane = tid & 63;
    const int wv   = tid >> 6;        // wave id 0..3
    const int r0   = blockIdx.x * 2;

    const int mult0 = obs[2 * r0];
    const int mult1 = obs[2 * r0 + 2];

    const float* g0 = z + (size_t)r0 * 3200;
    const float* g1 = g0 + 3200;

    // ---- async HBM -> LDS staging (prefix only, 1KB per wave-chunk) ----
    // chunk c covers floats [256c, 256c+256); needed iff 256c < mult*25
    const int nc0 = (mult0 * 25 + 255) >> 8;   // <= 13
    const int nc1 = (mult1 * 25 + 255) >> 8;
    for (int c = wv; c < nc0; c += 4) {
        const float* gp = g0 + (c << 8) + (lane << 2);
        __builtin_amdgcn_global_load_lds((as1_cvp)gp, (as3_vp)(s_z + (c << 8)),
                                         16, 0, 0);
    }
    for (int c = wv; c < nc1; c += 4) {
        const float* gp = g1 + (c << 8) + (lane << 2);
        // chunk 12 tail (lanes >= 32) would read past the buffer on the last
        // batch row; those LDS slots are never consumed -> clamp to row start
        if (c == 12 && lane >= 32) gp = g1;
        __builtin_amdgcn_global_load_lds((as1_cvp)gp, (as3_vp)(s_z + 3328 + (c << 8)),
                                         16, 0, 0);
    }

    // ---- per-thread (param,m) constants, overlapped with the DMA ----
    const int  half = tid >> 7;       // 0 -> row r0, 1 -> row r0+1
    const int  m    = tid & 127;
    const int  row  = r0 + half;
    const int  mult = half ? mult1 : mult0;
    const bool live = m < mult;

    const float pa = pa_p[0], pb = pb_p[0];
    const float a0 = base_p[0], b0 = base_p[1];
    const float an = (pa < AFROMZERO) ? 0.0f : pa;
    const float ao = (a0 < AFROMZERO) ? 0.0f : a0;

    const float mTv = mT[(size_t)row * 128 + m];
    float Cn2, ben2, Co2, beo2;
    set_consts2(pa, pb, mTv, Cn2, ben2);
    set_consts2(a0, b0, mTv, Co2, beo2);

    __syncthreads();   // compiler drains vmcnt(0) before s_barrier -> DMA complete

    float w = 1.0f;
    if (live) {
        // stride-25 floats across lanes: gcd(25,32)=1 -> 2 lanes/bank, conflict-free
        const float* zp = s_z + half * 3328 + m * 25;
        float facN = 1.0f, facD = 1.0f;
        #pragma unroll
        for (int k = 0; k < 25; ++k) {
            float zz  = zp[k];
            bool  act = (zz != 0.0f);
            float zs  = act ? zz : 0.5f;
            float rz  = __builtin_amdgcn_rcpf(zs);
            float lz  = __builtin_amdgcn_logf(zs);          // log2
            float l1  = __builtin_amdgcn_logf(1.0f - zs);   // log2
            float fn  = fmaf(-ben2, rz, Cn2) + fmaf(an, l1, -lz);
            float fo  = fmaf(-beo2, rz, Co2) + fmaf(ao, l1, -lz);
            fn = fminf(fmaxf(fn, -EXPMAX2), EXPMAX2);
            fo = fminf(fmaxf(fo, -EXPMAX2), EXPMAX2);
            float Ln = __builtin_amdgcn_exp2f(fn);
            float Lo = __builtin_amdgcn_exp2f(fo);
            float fN = (k == 0) ? Ln : (OSF - Ln);
            float fD = (k == 0) ? Lo : (OSF - Lo);
            facN *= act ? fN : 1.0f;
            facD *= act ? fD : 1.0f;
        }
        w = facN / facD;
    }

    // 64-lane product reduction (waves 0/1 -> row r0, waves 2/3 -> row r0+1)
    for (int mask = 1; mask < 64; mask <<= 1)
        w *= __shfl_xor(w, mask, 64);
    if ((tid & 63) == 0) s_part[tid >> 6] = w;
    __syncthreads();
    if (tid == 0)   out[r0]     = s_part[0] * s_part[1];
    if (tid == 128) out[r0 + 1] = s_part[2] * s_part[3];
}

extern "C" void kernel_launch(void* const* d_in, const int* in_sizes, int n_in,
                              void* d_out, int out_size, void* d_ws, size_t ws_size,
                              hipStream_t stream) {
    const float* z    = (const float*)d_in[0];
    const float* mT   = (const float*)d_in[1];
    const int*   obs  = (const int*)d_in[2];
    const float* pa   = (const float*)d_in[3];
    const float* pb   = (const float*)d_in[4];
    const float* base = (const float*)d_in[5];
    float* out = (float*)d_out;

    int B = in_sizes[0] / (128 * 25);   // z is (B, 128, 25)
    lund_weight_kernel<<<B / 2, 256, 0, stream>>>(z, mT, obs, pa, pb, base, out);
}